// Round 1
// baseline (740.110 us; speedup 1.0000x reference)
//
#include <hip/hip_runtime.h>
#include <math.h>

// ---------------------------------------------------------------------------
// GCN: 3x GCNConv (no nonlinearity) -> global_mean_pool -> linear -> sigmoid.
// Key identity: the net is linear up to the sigmoid, and A (node axis)
// commutes with W (feature axis):
//   h3 @ lin_w = A^3 (X u) + s2*A^2 1 + s1*A 1 + s0*1
//             = A(A(A(X u) + s2) + s1) + s0
// with u = W1 W2 W3 lin_w (4-vec), s2=b1'W2W3 lin_w, s1=b2'W3 lin_w, s0=b3'lin_w.
// So we propagate ONE float per node through 3 sparse passes.
// A t|_c = dinv_c * ( sum_{e: col=c} dinv_r t_r  +  dinv_c t_c )
// Using g = dinv .* t:  (A t)_c = dinv_c * (acc_c + g_c), acc_c = sum g_r.
// ---------------------------------------------------------------------------

__global__ void coeffs_kernel(const float* __restrict__ W1, const float* __restrict__ b1,
                              const float* __restrict__ W2, const float* __restrict__ b2,
                              const float* __restrict__ W3, const float* __restrict__ b3,
                              const float* __restrict__ lin_w, const float* __restrict__ lin_b,
                              float* __restrict__ coeff) {
    if (threadIdx.x == 0 && blockIdx.x == 0) {
        float w3l[16], w2l[16];
        for (int i = 0; i < 16; ++i) {
            float s = 0.f;
            for (int j = 0; j < 16; ++j) s += W3[i * 16 + j] * lin_w[j];
            w3l[i] = s;
        }
        for (int i = 0; i < 16; ++i) {
            float s = 0.f;
            for (int j = 0; j < 16; ++j) s += W2[i * 16 + j] * w3l[j];
            w2l[i] = s;
        }
        for (int i = 0; i < 4; ++i) {
            float s = 0.f;
            for (int j = 0; j < 16; ++j) s += W1[i * 16 + j] * w2l[j];
            coeff[i] = s;                       // u[0..3]
        }
        float s2 = 0.f, s1 = 0.f, s0 = 0.f;
        for (int j = 0; j < 16; ++j) {
            s2 += b1[j] * w2l[j];
            s1 += b2[j] * w3l[j];
            s0 += b3[j] * lin_w[j];
        }
        coeff[4] = s2;          // added after pass 1
        coeff[5] = s1;          // added after pass 2
        coeff[6] = s0;          // added after pass 3
        coeff[7] = lin_b[0];
    }
}

// deg = 1 (self loop); zero pool accumulators
__global__ void init_kernel(float* __restrict__ deg, float* __restrict__ sums,
                            float* __restrict__ cnt, int n, int ngraphs) {
    int i = blockIdx.x * blockDim.x + threadIdx.x;
    int stride = gridDim.x * blockDim.x;
    for (int k = i; k < n; k += stride) deg[k] = 1.0f;
    for (int k = i; k < ngraphs; k += stride) { sums[k] = 0.f; cnt[k] = 0.f; }
}

// deg[col[e]] += 1, vectorized int4 over col
__global__ void deg_kernel(const int* __restrict__ col, float* __restrict__ deg, int E) {
    int i = blockIdx.x * blockDim.x + threadIdx.x;
    int stride = gridDim.x * blockDim.x;
    int E4 = E >> 2;
    const int4* col4 = (const int4*)col;
    for (int k = i; k < E4; k += stride) {
        int4 c = col4[k];
        atomicAdd(&deg[c.x], 1.0f);
        atomicAdd(&deg[c.y], 1.0f);
        atomicAdd(&deg[c.z], 1.0f);
        atomicAdd(&deg[c.w], 1.0f);
    }
    for (int k = (E4 << 2) + i; k < E; k += stride) atomicAdd(&deg[col[k]], 1.0f);
}

// dinv = rsqrt(deg) (in place); t0 = x.u; g = dinv*t0; acc = 0
__global__ void node0_kernel(const float* __restrict__ x, const float* __restrict__ coeff,
                             float* __restrict__ deg_dinv, float* __restrict__ g,
                             float* __restrict__ acc, int n) {
    float u0 = coeff[0], u1 = coeff[1], u2 = coeff[2], u3 = coeff[3];
    int i = blockIdx.x * blockDim.x + threadIdx.x;
    int stride = gridDim.x * blockDim.x;
    const float4* x4 = (const float4*)x;
    for (int k = i; k < n; k += stride) {
        float d = rsqrtf(deg_dinv[k]);
        deg_dinv[k] = d;
        float4 xv = x4[k];
        float t0 = xv.x * u0 + xv.y * u1 + xv.z * u2 + xv.w * u3;
        g[k] = d * t0;
        acc[k] = 0.f;
    }
}

// acc[col] += g[row]; row = ei[0:E], col = ei[E:2E]; 4 edges/thread via int4
__global__ void edge_kernel(const int* __restrict__ ei, const float* __restrict__ g,
                            float* __restrict__ acc, int E) {
    int i = blockIdx.x * blockDim.x + threadIdx.x;
    int stride = gridDim.x * blockDim.x;
    int E4 = E >> 2;
    const int4* row4 = (const int4*)ei;
    const int4* col4 = (const int4*)(ei + E);
    for (int k = i; k < E4; k += stride) {
        int4 r = row4[k];
        int4 c = col4[k];
        atomicAdd(&acc[c.x], g[r.x]);
        atomicAdd(&acc[c.y], g[r.y]);
        atomicAdd(&acc[c.z], g[r.z]);
        atomicAdd(&acc[c.w], g[r.w]);
    }
    for (int k = (E4 << 2) + i; k < E; k += stride)
        atomicAdd(&acc[ei[E + k]], g[ei[k]]);
}

// t_new = dinv*(acc+g) + s; g = dinv*t_new; acc = 0
__global__ void node_kernel(const float* __restrict__ dinv, float* __restrict__ g,
                            float* __restrict__ acc, const float* __restrict__ coeff,
                            int sidx, int n) {
    float s = coeff[sidx];
    int i = blockIdx.x * blockDim.x + threadIdx.x;
    int stride = gridDim.x * blockDim.x;
    for (int k = i; k < n; k += stride) {
        float d = dinv[k];
        float t = d * (acc[k] + g[k]) + s;
        g[k] = d * t;
        acc[k] = 0.f;
    }
}

// t3 = dinv*(acc+g) + s0; pool into per-graph sums/counts
__global__ void pool_kernel(const float* __restrict__ dinv, const float* __restrict__ g,
                            const float* __restrict__ acc, const float* __restrict__ coeff,
                            const int* __restrict__ batch, float* __restrict__ sums,
                            float* __restrict__ cnt, int n) {
    float s0 = coeff[6];
    int i = blockIdx.x * blockDim.x + threadIdx.x;
    int stride = gridDim.x * blockDim.x;
    for (int k = i; k < n; k += stride) {
        float d = dinv[k];
        float t3 = d * (acc[k] + g[k]) + s0;
        int b = batch[k];
        atomicAdd(&sums[b], t3);
        atomicAdd(&cnt[b], 1.0f);
    }
}

__global__ void final_kernel(const float* __restrict__ sums, const float* __restrict__ cnt,
                             const float* __restrict__ coeff, float* __restrict__ out,
                             int ngraphs) {
    int i = blockIdx.x * blockDim.x + threadIdx.x;
    if (i < ngraphs) {
        float m = sums[i] / fmaxf(cnt[i], 1.0f) + coeff[7];
        out[i] = 1.0f / (1.0f + expf(-m));
    }
}

extern "C" void kernel_launch(void* const* d_in, const int* in_sizes, int n_in,
                              void* d_out, int out_size, void* d_ws, size_t ws_size,
                              hipStream_t stream) {
    const float* x     = (const float*)d_in[0];
    const int*   ei    = (const int*)d_in[1];
    const int*   batch = (const int*)d_in[2];
    const float* W1    = (const float*)d_in[3];
    const float* b1    = (const float*)d_in[4];
    const float* W2    = (const float*)d_in[5];
    const float* b2    = (const float*)d_in[6];
    const float* W3    = (const float*)d_in[7];
    const float* b3    = (const float*)d_in[8];
    const float* lin_w = (const float*)d_in[9];
    const float* lin_b = (const float*)d_in[10];

    const int n       = in_sizes[0] / 4;   // 100000 nodes
    const int E       = in_sizes[1] / 2;   // 3200000 edges
    const int ngraphs = out_size;          // 1000

    float* ws = (float*)d_ws;
    size_t npad = ((size_t)n + 255) & ~(size_t)255;
    size_t gpad = ((size_t)ngraphs + 255) & ~(size_t)255;
    float* coeff = ws;               // 256 floats
    float* deg   = coeff + 256;      // npad (deg -> dinv in place)
    float* g     = deg + npad;       // npad
    float* acc   = g + npad;         // npad
    float* sums  = acc + npad;       // gpad
    float* cnt   = sums + gpad;      // gpad

    const int B = 256;
    int nodeBlocks = (n + B - 1) / B;
    int edgeBlocks = ((E >> 2) + B - 1) / B;   // 4 edges/thread

    coeffs_kernel<<<1, 64, 0, stream>>>(W1, b1, W2, b2, W3, b3, lin_w, lin_b, coeff);
    init_kernel<<<nodeBlocks, B, 0, stream>>>(deg, sums, cnt, n, ngraphs);
    deg_kernel<<<edgeBlocks, B, 0, stream>>>(ei + E, deg, E);
    node0_kernel<<<nodeBlocks, B, 0, stream>>>(x, coeff, deg, g, acc, n);

    edge_kernel<<<edgeBlocks, B, 0, stream>>>(ei, g, acc, E);      // pass 1
    node_kernel<<<nodeBlocks, B, 0, stream>>>(deg, g, acc, coeff, 4, n);
    edge_kernel<<<edgeBlocks, B, 0, stream>>>(ei, g, acc, E);      // pass 2
    node_kernel<<<nodeBlocks, B, 0, stream>>>(deg, g, acc, coeff, 5, n);
    edge_kernel<<<edgeBlocks, B, 0, stream>>>(ei, g, acc, E);      // pass 3
    pool_kernel<<<nodeBlocks, B, 0, stream>>>(deg, g, acc, coeff, batch, sums, cnt, n);

    final_kernel<<<(ngraphs + B - 1) / B, B, 0, stream>>>(sums, cnt, coeff, d_out ? (float*)d_out : nullptr, ngraphs);
}

// Round 2
// 279.025 us; speedup vs baseline: 2.6525x; 2.6525x over previous
//
#include <hip/hip_runtime.h>
#include <math.h>

// ---------------------------------------------------------------------------
// GCN: 3x GCNConv (linear) -> mean pool -> linear -> sigmoid.
// Linear-collapse identity (proved in R1, absmax 0.0):
//   h3 @ lin_w = A(A(A(X u) + s2) + s1) + s0,  u = W1W2W3 lin_w.
// R1 bottleneck: per-edge device-scope atomicAdd = 32B fabric write each
// (WRITE_SIZE ~= E*32B per pass). Fix: bucket edges by dest (col>>6) via
// LDS-histogram radix, then all propagation passes are atomic-free gathers
// with LDS accumulation (one block per 64-node bucket).
// ---------------------------------------------------------------------------

#define SHIFT      6
#define BSZ        64          // nodes per bucket = 1<<SHIFT
#define NB_SCAT    512         // blocks for hist/scatter phases
#define SCAN_CHUNK 2048

__global__ void coeffs_kernel(const float* __restrict__ W1, const float* __restrict__ b1,
                              const float* __restrict__ W2, const float* __restrict__ b2,
                              const float* __restrict__ W3, const float* __restrict__ b3,
                              const float* __restrict__ lin_w, const float* __restrict__ lin_b,
                              float* __restrict__ coeff) {
    if (threadIdx.x == 0 && blockIdx.x == 0) {
        float w3l[16], w2l[16];
        for (int i = 0; i < 16; ++i) {
            float s = 0.f;
            for (int j = 0; j < 16; ++j) s += W3[i * 16 + j] * lin_w[j];
            w3l[i] = s;
        }
        for (int i = 0; i < 16; ++i) {
            float s = 0.f;
            for (int j = 0; j < 16; ++j) s += W2[i * 16 + j] * w3l[j];
            w2l[i] = s;
        }
        for (int i = 0; i < 4; ++i) {
            float s = 0.f;
            for (int j = 0; j < 16; ++j) s += W1[i * 16 + j] * w2l[j];
            coeff[i] = s;
        }
        float s2 = 0.f, s1 = 0.f, s0 = 0.f;
        for (int j = 0; j < 16; ++j) {
            s2 += b1[j] * w2l[j];
            s1 += b2[j] * w3l[j];
            s0 += b3[j] * lin_w[j];
        }
        coeff[4] = s2; coeff[5] = s1; coeff[6] = s0; coeff[7] = lin_b[0];
    }
}

__global__ void zero_pool_kernel(float* __restrict__ sums, float* __restrict__ cnt, int ngraphs) {
    int i = blockIdx.x * blockDim.x + threadIdx.x;
    if (i < ngraphs) { sums[i] = 0.f; cnt[i] = 0.f; }
}

// ---- Phase A: per-block histogram of col>>SHIFT. M layout: [bin][block].
__global__ void hist_kernel(const int* __restrict__ col, int E, int tile, int nbuck,
                            unsigned* __restrict__ M) {
    extern __shared__ unsigned h[];
    for (int i = threadIdx.x; i < nbuck; i += blockDim.x) h[i] = 0;
    __syncthreads();
    int b = blockIdx.x;
    int s = b * tile, e = min(s + tile, E);
    for (int k = s + threadIdx.x; k < e; k += blockDim.x)
        atomicAdd(&h[((unsigned)col[k]) >> SHIFT], 1u);
    __syncthreads();
    for (int i = threadIdx.x; i < nbuck; i += blockDim.x)
        M[(size_t)i * NB_SCAT + b] = h[i];
}

// ---- exclusive scan over M (nbuck*NB_SCAT elems), 3-kernel hierarchy
__global__ void scan1_kernel(const unsigned* __restrict__ M, unsigned* __restrict__ part,
                             int total, int chunk) {
    __shared__ unsigned sdata[256];
    int b = blockIdx.x;
    int s = b * chunk, e = min(s + chunk, total);
    unsigned sum = 0;
    for (int k = s + threadIdx.x; k < e; k += blockDim.x) sum += M[k];
    sdata[threadIdx.x] = sum;
    __syncthreads();
    for (int off = 128; off > 0; off >>= 1) {
        if (threadIdx.x < off) sdata[threadIdx.x] += sdata[threadIdx.x + off];
        __syncthreads();
    }
    if (threadIdx.x == 0) part[b] = sdata[0];
}

__global__ void scan2_kernel(unsigned* __restrict__ part, int np) {
    if (threadIdx.x == 0 && blockIdx.x == 0) {
        unsigned run = 0;
        for (int i = 0; i < np; ++i) { unsigned v = part[i]; part[i] = run; run += v; }
    }
}

__global__ void scan3_kernel(unsigned* __restrict__ M, const unsigned* __restrict__ part,
                             int total, int chunk) {
    __shared__ unsigned ts[256];
    int b = blockIdx.x;
    int s = b * chunk;
    const int per = SCAN_CHUNK / 256;      // 8
    unsigned v[per];
    unsigned sum = 0;
    int base = s + threadIdx.x * per;
    for (int j = 0; j < per; ++j) {
        unsigned x = (base + j < total) ? M[base + j] : 0u;
        v[j] = sum; sum += x;
    }
    ts[threadIdx.x] = sum;
    __syncthreads();
    for (int off = 1; off < 256; off <<= 1) {
        unsigned t = (threadIdx.x >= (unsigned)off) ? ts[threadIdx.x - off] : 0u;
        __syncthreads();
        ts[threadIdx.x] += t;
        __syncthreads();
    }
    unsigned texcl = (threadIdx.x == 0) ? 0u : ts[threadIdx.x - 1];
    unsigned pb = part[b];
    for (int j = 0; j < per; ++j)
        if (base + j < total) M[base + j] = pb + texcl + v[j];
}

// ---- Phase B: stable-ish scatter into buckets; pack row(17b) | col_low(6b)<<17
__global__ void scatter_kernel(const int* __restrict__ row, const int* __restrict__ col,
                               int E, int tile, int nbuck, const unsigned* __restrict__ M,
                               unsigned* __restrict__ out) {
    extern __shared__ unsigned base[];
    int b = blockIdx.x;
    for (int i = threadIdx.x; i < nbuck; i += blockDim.x)
        base[i] = M[(size_t)i * NB_SCAT + b];
    __syncthreads();
    int s = b * tile, e = min(s + tile, E);
    for (int k = s + threadIdx.x; k < e; k += blockDim.x) {
        unsigned c = (unsigned)col[k];
        unsigned pos = atomicAdd(&base[c >> SHIFT], 1u);
        out[pos] = (unsigned)row[k] | ((c & (BSZ - 1)) << 17);
    }
}

// ---- deg (incoming count +1 self) -> dinv; fused with t0 = x.u, g0 = dinv*t0
__global__ void deg0_kernel(const unsigned* __restrict__ buck, const unsigned* __restrict__ M,
                            int nbuck, int E, const float* __restrict__ x,
                            const float* __restrict__ coeff, float* __restrict__ dinv,
                            float* __restrict__ g, int n) {
    __shared__ float acc[BSZ];
    int b = blockIdx.x;
    if (threadIdx.x < BSZ) acc[threadIdx.x] = 0.f;
    __syncthreads();
    unsigned s = M[(size_t)b * NB_SCAT];
    unsigned e = (b + 1 < nbuck) ? M[(size_t)(b + 1) * NB_SCAT] : (unsigned)E;
    for (unsigned k = s + threadIdx.x; k < e; k += blockDim.x)
        atomicAdd(&acc[buck[k] >> 17], 1.0f);
    __syncthreads();
    if (threadIdx.x < BSZ) {
        int node = b * BSZ + threadIdx.x;
        if (node < n) {
            float d = rsqrtf(acc[threadIdx.x] + 1.0f);
            dinv[node] = d;
            float4 xv = ((const float4*)x)[node];
            float t0 = xv.x * coeff[0] + xv.y * coeff[1] + xv.z * coeff[2] + xv.w * coeff[3];
            g[node] = d * t0;
        }
    }
}

// ---- one propagation pass: acc_c = sum g[row]; t = dinv*(acc+g)+s
// passes 1,2: gout = dinv*t.  pass 3: pool t into sums/cnt.
__global__ void gather_kernel(const unsigned* __restrict__ buck, const unsigned* __restrict__ M,
                              int nbuck, int E, const float* __restrict__ dinv,
                              const float* __restrict__ gin, float* __restrict__ gout,
                              const float* __restrict__ coeff, int sidx, int n, int lastPass,
                              const int* __restrict__ batch, float* __restrict__ sums,
                              float* __restrict__ cnt) {
    __shared__ float acc[BSZ];
    int b = blockIdx.x;
    if (threadIdx.x < BSZ) acc[threadIdx.x] = 0.f;
    __syncthreads();
    unsigned s = M[(size_t)b * NB_SCAT];
    unsigned e = (b + 1 < nbuck) ? M[(size_t)(b + 1) * NB_SCAT] : (unsigned)E;
    for (unsigned k = s + threadIdx.x; k < e; k += blockDim.x) {
        unsigned w = buck[k];
        atomicAdd(&acc[w >> 17], gin[w & 0x1FFFFu]);
    }
    __syncthreads();
    if (threadIdx.x < BSZ) {
        int node = b * BSZ + threadIdx.x;
        if (node < n) {
            float d = dinv[node];
            float t = d * (acc[threadIdx.x] + gin[node]) + coeff[sidx];
            if (!lastPass) {
                gout[node] = d * t;
            } else {
                int bb = batch[node];
                atomicAdd(&sums[bb], t);
                atomicAdd(&cnt[bb], 1.0f);
            }
        }
    }
}

__global__ void final_kernel(const float* __restrict__ sums, const float* __restrict__ cnt,
                             const float* __restrict__ coeff, float* __restrict__ out,
                             int ngraphs) {
    int i = blockIdx.x * blockDim.x + threadIdx.x;
    if (i < ngraphs) {
        float m = sums[i] / fmaxf(cnt[i], 1.0f) + coeff[7];
        out[i] = 1.0f / (1.0f + expf(-m));
    }
}

// ======================= R1 fallback (atomic path) =========================
__global__ void fb_init_kernel(float* __restrict__ deg, float* __restrict__ sums,
                               float* __restrict__ cnt, int n, int ngraphs) {
    int i = blockIdx.x * blockDim.x + threadIdx.x;
    int stride = gridDim.x * blockDim.x;
    for (int k = i; k < n; k += stride) deg[k] = 1.0f;
    for (int k = i; k < ngraphs; k += stride) { sums[k] = 0.f; cnt[k] = 0.f; }
}
__global__ void fb_deg_kernel(const int* __restrict__ col, float* __restrict__ deg, int E) {
    int i = blockIdx.x * blockDim.x + threadIdx.x;
    int stride = gridDim.x * blockDim.x;
    for (int k = i; k < E; k += stride) atomicAdd(&deg[col[k]], 1.0f);
}
__global__ void fb_node0_kernel(const float* __restrict__ x, const float* __restrict__ coeff,
                                float* __restrict__ deg_dinv, float* __restrict__ g,
                                float* __restrict__ acc, int n) {
    int i = blockIdx.x * blockDim.x + threadIdx.x;
    int stride = gridDim.x * blockDim.x;
    for (int k = i; k < n; k += stride) {
        float d = rsqrtf(deg_dinv[k]);
        deg_dinv[k] = d;
        float4 xv = ((const float4*)x)[k];
        float t0 = xv.x * coeff[0] + xv.y * coeff[1] + xv.z * coeff[2] + xv.w * coeff[3];
        g[k] = d * t0;
        acc[k] = 0.f;
    }
}
__global__ void fb_edge_kernel(const int* __restrict__ ei, const float* __restrict__ g,
                               float* __restrict__ acc, int E) {
    int i = blockIdx.x * blockDim.x + threadIdx.x;
    int stride = gridDim.x * blockDim.x;
    for (int k = i; k < E; k += stride) atomicAdd(&acc[ei[E + k]], g[ei[k]]);
}
__global__ void fb_node_kernel(const float* __restrict__ dinv, float* __restrict__ g,
                               float* __restrict__ acc, const float* __restrict__ coeff,
                               int sidx, int n) {
    int i = blockIdx.x * blockDim.x + threadIdx.x;
    int stride = gridDim.x * blockDim.x;
    for (int k = i; k < n; k += stride) {
        float d = dinv[k];
        float t = d * (acc[k] + g[k]) + coeff[sidx];
        g[k] = d * t;
        acc[k] = 0.f;
    }
}
__global__ void fb_pool_kernel(const float* __restrict__ dinv, const float* __restrict__ g,
                               const float* __restrict__ acc, const float* __restrict__ coeff,
                               const int* __restrict__ batch, float* __restrict__ sums,
                               float* __restrict__ cnt, int n) {
    int i = blockIdx.x * blockDim.x + threadIdx.x;
    int stride = gridDim.x * blockDim.x;
    for (int k = i; k < n; k += stride) {
        float d = dinv[k];
        float t3 = d * (acc[k] + g[k]) + coeff[6];
        int b = batch[k];
        atomicAdd(&sums[b], t3);
        atomicAdd(&cnt[b], 1.0f);
    }
}
// ===========================================================================

extern "C" void kernel_launch(void* const* d_in, const int* in_sizes, int n_in,
                              void* d_out, int out_size, void* d_ws, size_t ws_size,
                              hipStream_t stream) {
    const float* x     = (const float*)d_in[0];
    const int*   ei    = (const int*)d_in[1];
    const int*   batch = (const int*)d_in[2];
    const float* W1    = (const float*)d_in[3];
    const float* b1    = (const float*)d_in[4];
    const float* W2    = (const float*)d_in[5];
    const float* b2    = (const float*)d_in[6];
    const float* W3    = (const float*)d_in[7];
    const float* b3    = (const float*)d_in[8];
    const float* lin_w = (const float*)d_in[9];
    const float* lin_b = (const float*)d_in[10];

    const int n       = in_sizes[0] / 4;   // 100000
    const int E       = in_sizes[1] / 2;   // 3200000
    const int ngraphs = out_size;          // 1000

    const int nbuck = (n + BSZ - 1) / BSZ;
    const int B = 256;

    size_t npad = ((size_t)n + 255) & ~(size_t)255;
    size_t gpad = ((size_t)ngraphs + 255) & ~(size_t)255;
    size_t mlen = (size_t)nbuck * NB_SCAT;
    int total   = (int)mlen;
    int nchunks = (total + SCAN_CHUNK - 1) / SCAN_CHUNK;

    // workspace layout (floats/u32, 256-elem aligned slabs)
    size_t need = (256 + mlen + 1024 + (size_t)E + 3 * npad + 2 * gpad) * 4;

    float* ws   = (float*)d_ws;
    float* coeff = ws;                                    // 256
    unsigned* M    = (unsigned*)(coeff + 256);            // mlen
    unsigned* part = M + mlen;                            // <=1024
    unsigned* buck = part + 1024;                         // E
    float* dinv  = (float*)(buck + E);                    // npad
    float* gA    = dinv + npad;                           // npad
    float* gB    = gA + npad;                             // npad
    float* sums  = gB + npad;                             // gpad
    float* cnt   = sums + gpad;                           // gpad

    coeffs_kernel<<<1, 64, 0, stream>>>(W1, b1, W2, b2, W3, b3, lin_w, lin_b, coeff);

    if (ws_size < need) {
        // -------- fallback: R1 atomic path (needs ~1.2 MB) --------
        float* deg = (float*)(ws + 256);
        float* g   = deg + npad;
        float* acc = g + npad;
        float* fsums = acc + npad;
        float* fcnt  = fsums + gpad;
        int nodeBlocks = (n + B - 1) / B;
        int edgeBlocks = (E + B - 1) / B;
        fb_init_kernel<<<nodeBlocks, B, 0, stream>>>(deg, fsums, fcnt, n, ngraphs);
        fb_deg_kernel<<<edgeBlocks, B, 0, stream>>>(ei + E, deg, E);
        fb_node0_kernel<<<nodeBlocks, B, 0, stream>>>(x, coeff, deg, g, acc, n);
        fb_edge_kernel<<<edgeBlocks, B, 0, stream>>>(ei, g, acc, E);
        fb_node_kernel<<<nodeBlocks, B, 0, stream>>>(deg, g, acc, coeff, 4, n);
        fb_edge_kernel<<<edgeBlocks, B, 0, stream>>>(ei, g, acc, E);
        fb_node_kernel<<<nodeBlocks, B, 0, stream>>>(deg, g, acc, coeff, 5, n);
        fb_edge_kernel<<<edgeBlocks, B, 0, stream>>>(ei, g, acc, E);
        fb_pool_kernel<<<nodeBlocks, B, 0, stream>>>(deg, g, acc, coeff, batch, fsums, fcnt, n);
        final_kernel<<<(ngraphs + B - 1) / B, B, 0, stream>>>(fsums, fcnt, coeff, (float*)d_out, ngraphs);
        return;
    }

    int tile = (E + NB_SCAT - 1) / NB_SCAT;
    size_t ldsHist = (size_t)nbuck * sizeof(unsigned);

    zero_pool_kernel<<<(ngraphs + B - 1) / B, B, 0, stream>>>(sums, cnt, ngraphs);

    hist_kernel<<<NB_SCAT, B, ldsHist, stream>>>(ei + E, E, tile, nbuck, M);
    scan1_kernel<<<nchunks, B, 0, stream>>>(M, part, total, SCAN_CHUNK);
    scan2_kernel<<<1, 64, 0, stream>>>(part, nchunks);
    scan3_kernel<<<nchunks, B, 0, stream>>>(M, part, total, SCAN_CHUNK);
    scatter_kernel<<<NB_SCAT, B, ldsHist, stream>>>(ei, ei + E, E, tile, nbuck, M, buck);

    deg0_kernel<<<nbuck, B, 0, stream>>>(buck, M, nbuck, E, x, coeff, dinv, gA, n);

    gather_kernel<<<nbuck, B, 0, stream>>>(buck, M, nbuck, E, dinv, gA, gB, coeff, 4, n, 0,
                                           batch, sums, cnt);
    gather_kernel<<<nbuck, B, 0, stream>>>(buck, M, nbuck, E, dinv, gB, gA, coeff, 5, n, 0,
                                           batch, sums, cnt);
    gather_kernel<<<nbuck, B, 0, stream>>>(buck, M, nbuck, E, dinv, gA, gB, coeff, 6, n, 1,
                                           batch, sums, cnt);

    final_kernel<<<(ngraphs + B - 1) / B, B, 0, stream>>>(sums, cnt, coeff, (float*)d_out, ngraphs);
}

// Round 3
// 179.864 us; speedup vs baseline: 4.1148x; 1.5513x over previous
//
#include <hip/hip_runtime.h>
#include <math.h>

// ---------------------------------------------------------------------------
// GCN: 3x GCNConv (linear) -> mean pool -> linear -> sigmoid.
// Linear-collapse identity (absmax 0.0 in R1/R2):
//   h3 @ lin_w = A(A(A(X u) + s2) + s1) + s0,  u = W1W2W3 lin_w.
// R2 profile: lastPass gather = 100us (200K device atomics into 1000 slots,
// WRITE_SIZE 5.9MB = 32B/atomic fabric writes); other gathers latency-bound
// (VALUBusy 0.6%, 1 dependent random load per iter).
// R3: (a) segmented pool via sorted batch (LDS slots + ~5K sparse atomics),
//     (b) uint4 x4 unroll in all edge loops for memory-level parallelism.
// ---------------------------------------------------------------------------

#define SHIFT      6
#define BSZ        64          // nodes per bucket = 1<<SHIFT
#define NB_SCAT    256         // blocks for hist/scatter phases
#define SCAN_CHUNK 2048
#define PNODES     1024        // nodes per pool block

__global__ void coeffs_kernel(const float* __restrict__ W1, const float* __restrict__ b1,
                              const float* __restrict__ W2, const float* __restrict__ b2,
                              const float* __restrict__ W3, const float* __restrict__ b3,
                              const float* __restrict__ lin_w, const float* __restrict__ lin_b,
                              float* __restrict__ coeff) {
    if (threadIdx.x == 0 && blockIdx.x == 0) {
        float w3l[16], w2l[16];
        for (int i = 0; i < 16; ++i) {
            float s = 0.f;
            for (int j = 0; j < 16; ++j) s += W3[i * 16 + j] * lin_w[j];
            w3l[i] = s;
        }
        for (int i = 0; i < 16; ++i) {
            float s = 0.f;
            for (int j = 0; j < 16; ++j) s += W2[i * 16 + j] * w3l[j];
            w2l[i] = s;
        }
        for (int i = 0; i < 4; ++i) {
            float s = 0.f;
            for (int j = 0; j < 16; ++j) s += W1[i * 16 + j] * w2l[j];
            coeff[i] = s;
        }
        float s2 = 0.f, s1 = 0.f, s0 = 0.f;
        for (int j = 0; j < 16; ++j) {
            s2 += b1[j] * w2l[j];
            s1 += b2[j] * w3l[j];
            s0 += b3[j] * lin_w[j];
        }
        coeff[4] = s2; coeff[5] = s1; coeff[6] = s0; coeff[7] = lin_b[0];
    }
}

__global__ void zero_pool_kernel(float* __restrict__ sums, float* __restrict__ cnt, int ngraphs) {
    int i = blockIdx.x * blockDim.x + threadIdx.x;
    if (i < ngraphs) { sums[i] = 0.f; cnt[i] = 0.f; }
}

// ---- Phase A: per-block histogram of col>>SHIFT. M layout: [bin][block].
__global__ void hist_kernel(const int* __restrict__ col, int E, int tile, int nbuck,
                            unsigned* __restrict__ M) {
    extern __shared__ unsigned h[];
    for (int i = threadIdx.x; i < nbuck; i += blockDim.x) h[i] = 0;
    __syncthreads();
    int b = blockIdx.x;
    int s = b * tile, e = min(s + tile, E);          // s is multiple of 4 (tile rounded)
    if (s < e) {
        int nq = (e - s) >> 2;
        const int4* c4 = (const int4*)(col + s);
        for (int q = threadIdx.x; q < nq; q += blockDim.x) {
            int4 c = c4[q];
            atomicAdd(&h[((unsigned)c.x) >> SHIFT], 1u);
            atomicAdd(&h[((unsigned)c.y) >> SHIFT], 1u);
            atomicAdd(&h[((unsigned)c.z) >> SHIFT], 1u);
            atomicAdd(&h[((unsigned)c.w) >> SHIFT], 1u);
        }
        for (int k = s + (nq << 2) + threadIdx.x; k < e; k += blockDim.x)
            atomicAdd(&h[((unsigned)col[k]) >> SHIFT], 1u);
    }
    __syncthreads();
    for (int i = threadIdx.x; i < nbuck; i += blockDim.x)
        M[(size_t)i * NB_SCAT + b] = h[i];
}

// ---- exclusive scan over M (nbuck*NB_SCAT elems), 3-kernel hierarchy
__global__ void scan1_kernel(const unsigned* __restrict__ M, unsigned* __restrict__ part,
                             int total, int chunk) {
    __shared__ unsigned sdata[256];
    int b = blockIdx.x;
    int s = b * chunk, e = min(s + chunk, total);
    unsigned sum = 0;
    for (int k = s + threadIdx.x; k < e; k += blockDim.x) sum += M[k];
    sdata[threadIdx.x] = sum;
    __syncthreads();
    for (int off = 128; off > 0; off >>= 1) {
        if (threadIdx.x < off) sdata[threadIdx.x] += sdata[threadIdx.x + off];
        __syncthreads();
    }
    if (threadIdx.x == 0) part[b] = sdata[0];
}

__global__ void scan2_kernel(unsigned* __restrict__ part, int np) {
    if (threadIdx.x == 0 && blockIdx.x == 0) {
        unsigned run = 0;
        for (int i = 0; i < np; ++i) { unsigned v = part[i]; part[i] = run; run += v; }
    }
}

__global__ void scan3_kernel(unsigned* __restrict__ M, const unsigned* __restrict__ part,
                             int total, int chunk) {
    __shared__ unsigned ts[256];
    int b = blockIdx.x;
    int s = b * chunk;
    const int per = SCAN_CHUNK / 256;      // 8
    unsigned v[per];
    unsigned sum = 0;
    int base = s + threadIdx.x * per;
    for (int j = 0; j < per; ++j) {
        unsigned x = (base + j < total) ? M[base + j] : 0u;
        v[j] = sum; sum += x;
    }
    ts[threadIdx.x] = sum;
    __syncthreads();
    for (int off = 1; off < 256; off <<= 1) {
        unsigned t = (threadIdx.x >= (unsigned)off) ? ts[threadIdx.x - off] : 0u;
        __syncthreads();
        ts[threadIdx.x] += t;
        __syncthreads();
    }
    unsigned texcl = (threadIdx.x == 0) ? 0u : ts[threadIdx.x - 1];
    unsigned pb = part[b];
    for (int j = 0; j < per; ++j)
        if (base + j < total) M[base + j] = pb + texcl + v[j];
}

// ---- Phase B: scatter into buckets; pack row(17b) | col_low(6b)<<17
__global__ void scatter_kernel(const int* __restrict__ row, const int* __restrict__ col,
                               int E, int tile, int nbuck, const unsigned* __restrict__ M,
                               unsigned* __restrict__ out) {
    extern __shared__ unsigned base[];
    int b = blockIdx.x;
    for (int i = threadIdx.x; i < nbuck; i += blockDim.x)
        base[i] = M[(size_t)i * NB_SCAT + b];
    __syncthreads();
    int s = b * tile, e = min(s + tile, E);
    if (s < e) {
        int nq = (e - s) >> 2;
        const int4* r4 = (const int4*)(row + s);
        const int4* c4 = (const int4*)(col + s);
        for (int q = threadIdx.x; q < nq; q += blockDim.x) {
            int4 r = r4[q];
            int4 c = c4[q];
            unsigned p0 = atomicAdd(&base[((unsigned)c.x) >> SHIFT], 1u);
            unsigned p1 = atomicAdd(&base[((unsigned)c.y) >> SHIFT], 1u);
            unsigned p2 = atomicAdd(&base[((unsigned)c.z) >> SHIFT], 1u);
            unsigned p3 = atomicAdd(&base[((unsigned)c.w) >> SHIFT], 1u);
            out[p0] = (unsigned)r.x | (((unsigned)c.x & (BSZ - 1)) << 17);
            out[p1] = (unsigned)r.y | (((unsigned)c.y & (BSZ - 1)) << 17);
            out[p2] = (unsigned)r.z | (((unsigned)c.z & (BSZ - 1)) << 17);
            out[p3] = (unsigned)r.w | (((unsigned)c.w & (BSZ - 1)) << 17);
        }
        for (int k = s + (nq << 2) + threadIdx.x; k < e; k += blockDim.x) {
            unsigned c = (unsigned)col[k];
            unsigned pos = atomicAdd(&base[c >> SHIFT], 1u);
            out[pos] = (unsigned)row[k] | ((c & (BSZ - 1)) << 17);
        }
    }
}

// ---- deg (incoming count +1 self) -> dinv; fused with t0 = x.u, g0 = dinv*t0
__global__ void deg0_kernel(const unsigned* __restrict__ buck, const unsigned* __restrict__ M,
                            int nbuck, int E, const float* __restrict__ x,
                            const float* __restrict__ coeff, float* __restrict__ dinv,
                            float* __restrict__ g, int n) {
    __shared__ float acc[BSZ];
    int b = blockIdx.x;
    if (threadIdx.x < BSZ) acc[threadIdx.x] = 0.f;
    __syncthreads();
    unsigned s = M[(size_t)b * NB_SCAT];
    unsigned e = (b + 1 < nbuck) ? M[(size_t)(b + 1) * NB_SCAT] : (unsigned)E;
    unsigned sa = (s + 3u) & ~3u;
    if (sa > e) sa = e;
    if (s + threadIdx.x < sa)
        atomicAdd(&acc[buck[s + threadIdx.x] >> 17], 1.0f);
    unsigned nq = (e - sa) >> 2;
    const uint4* bq = (const uint4*)(buck + sa);
    for (unsigned q = threadIdx.x; q < nq; q += blockDim.x) {
        uint4 w = bq[q];
        atomicAdd(&acc[w.x >> 17], 1.0f);
        atomicAdd(&acc[w.y >> 17], 1.0f);
        atomicAdd(&acc[w.z >> 17], 1.0f);
        atomicAdd(&acc[w.w >> 17], 1.0f);
    }
    for (unsigned k = sa + (nq << 2) + threadIdx.x; k < e; k += blockDim.x)
        atomicAdd(&acc[buck[k] >> 17], 1.0f);
    __syncthreads();
    if (threadIdx.x < BSZ) {
        int node = b * BSZ + threadIdx.x;
        if (node < n) {
            float d = rsqrtf(acc[threadIdx.x] + 1.0f);
            dinv[node] = d;
            float4 xv = ((const float4*)x)[node];
            float t0 = xv.x * coeff[0] + xv.y * coeff[1] + xv.z * coeff[2] + xv.w * coeff[3];
            g[node] = d * t0;
        }
    }
}

// ---- one propagation pass: acc_c = sum g[row]; t = dinv*(acc+g)+s
// passes 1,2: gout = dinv*t.  pass 3 (lastPass): gout = t (t3, pooled later).
__global__ void gather_kernel(const unsigned* __restrict__ buck, const unsigned* __restrict__ M,
                              int nbuck, int E, const float* __restrict__ dinv,
                              const float* __restrict__ gin, float* __restrict__ gout,
                              const float* __restrict__ coeff, int sidx, int n, int lastPass) {
    __shared__ float acc[BSZ];
    int b = blockIdx.x;
    if (threadIdx.x < BSZ) acc[threadIdx.x] = 0.f;
    __syncthreads();
    unsigned s = M[(size_t)b * NB_SCAT];
    unsigned e = (b + 1 < nbuck) ? M[(size_t)(b + 1) * NB_SCAT] : (unsigned)E;
    unsigned sa = (s + 3u) & ~3u;
    if (sa > e) sa = e;
    if (s + threadIdx.x < sa) {
        unsigned w = buck[s + threadIdx.x];
        atomicAdd(&acc[w >> 17], gin[w & 0x1FFFFu]);
    }
    unsigned nq = (e - sa) >> 2;
    const uint4* bq = (const uint4*)(buck + sa);
    for (unsigned q = threadIdx.x; q < nq; q += blockDim.x) {
        uint4 w = bq[q];
        float a0 = gin[w.x & 0x1FFFFu];     // 4 independent gathers in flight
        float a1 = gin[w.y & 0x1FFFFu];
        float a2 = gin[w.z & 0x1FFFFu];
        float a3 = gin[w.w & 0x1FFFFu];
        atomicAdd(&acc[w.x >> 17], a0);
        atomicAdd(&acc[w.y >> 17], a1);
        atomicAdd(&acc[w.z >> 17], a2);
        atomicAdd(&acc[w.w >> 17], a3);
    }
    for (unsigned k = sa + (nq << 2) + threadIdx.x; k < e; k += blockDim.x) {
        unsigned w = buck[k];
        atomicAdd(&acc[w >> 17], gin[w & 0x1FFFFu]);
    }
    __syncthreads();
    if (threadIdx.x < BSZ) {
        int node = b * BSZ + threadIdx.x;
        if (node < n) {
            float d = dinv[node];
            float t = d * (acc[threadIdx.x] + gin[node]) + coeff[sidx];
            gout[node] = lastPass ? t : d * t;
        }
    }
}

// ---- segmented mean-pool using SORTED batch: LDS slots + sparse atomics
__global__ void pool_kernel(const float* __restrict__ t3, const int* __restrict__ batch,
                            float* __restrict__ sums, float* __restrict__ cnt, int n) {
    __shared__ float ls[1024];
    __shared__ float lc[1024];
    int s = blockIdx.x * PNODES, e = min(s + PNODES, n);
    if (s >= e) return;
    int bFirst = batch[s];
    int bLast  = batch[e - 1];
    int range = bLast - bFirst + 1;
    if (range <= 1024) {
        for (int i = threadIdx.x; i < range; i += blockDim.x) { ls[i] = 0.f; lc[i] = 0.f; }
        __syncthreads();
        for (int k = s + threadIdx.x; k < e; k += blockDim.x) {
            int bb = batch[k] - bFirst;
            atomicAdd(&ls[bb], t3[k]);
            atomicAdd(&lc[bb], 1.0f);
        }
        __syncthreads();
        for (int i = threadIdx.x; i < range; i += blockDim.x) {
            if (lc[i] != 0.f) {
                atomicAdd(&sums[bFirst + i], ls[i]);
                atomicAdd(&cnt[bFirst + i], lc[i]);
            }
        }
    } else {  // defensive fallback (unreachable for ngraphs<=1024)
        for (int k = s + threadIdx.x; k < e; k += blockDim.x) {
            atomicAdd(&sums[batch[k]], t3[k]);
            atomicAdd(&cnt[batch[k]], 1.0f);
        }
    }
}

__global__ void final_kernel(const float* __restrict__ sums, const float* __restrict__ cnt,
                             const float* __restrict__ coeff, float* __restrict__ out,
                             int ngraphs) {
    int i = blockIdx.x * blockDim.x + threadIdx.x;
    if (i < ngraphs) {
        float m = sums[i] / fmaxf(cnt[i], 1.0f) + coeff[7];
        out[i] = 1.0f / (1.0f + expf(-m));
    }
}

// ======================= R1 fallback (atomic path) =========================
__global__ void fb_init_kernel(float* __restrict__ deg, float* __restrict__ sums,
                               float* __restrict__ cnt, int n, int ngraphs) {
    int i = blockIdx.x * blockDim.x + threadIdx.x;
    int stride = gridDim.x * blockDim.x;
    for (int k = i; k < n; k += stride) deg[k] = 1.0f;
    for (int k = i; k < ngraphs; k += stride) { sums[k] = 0.f; cnt[k] = 0.f; }
}
__global__ void fb_deg_kernel(const int* __restrict__ col, float* __restrict__ deg, int E) {
    int i = blockIdx.x * blockDim.x + threadIdx.x;
    int stride = gridDim.x * blockDim.x;
    for (int k = i; k < E; k += stride) atomicAdd(&deg[col[k]], 1.0f);
}
__global__ void fb_node0_kernel(const float* __restrict__ x, const float* __restrict__ coeff,
                                float* __restrict__ deg_dinv, float* __restrict__ g,
                                float* __restrict__ acc, int n) {
    int i = blockIdx.x * blockDim.x + threadIdx.x;
    int stride = gridDim.x * blockDim.x;
    for (int k = i; k < n; k += stride) {
        float d = rsqrtf(deg_dinv[k]);
        deg_dinv[k] = d;
        float4 xv = ((const float4*)x)[k];
        float t0 = xv.x * coeff[0] + xv.y * coeff[1] + xv.z * coeff[2] + xv.w * coeff[3];
        g[k] = d * t0;
        acc[k] = 0.f;
    }
}
__global__ void fb_edge_kernel(const int* __restrict__ ei, const float* __restrict__ g,
                               float* __restrict__ acc, int E) {
    int i = blockIdx.x * blockDim.x + threadIdx.x;
    int stride = gridDim.x * blockDim.x;
    for (int k = i; k < E; k += stride) atomicAdd(&acc[ei[E + k]], g[ei[k]]);
}
__global__ void fb_node_kernel(const float* __restrict__ dinv, float* __restrict__ g,
                               float* __restrict__ acc, const float* __restrict__ coeff,
                               int sidx, int n) {
    int i = blockIdx.x * blockDim.x + threadIdx.x;
    int stride = gridDim.x * blockDim.x;
    for (int k = i; k < n; k += stride) {
        float d = dinv[k];
        float t = d * (acc[k] + g[k]) + coeff[sidx];
        g[k] = d * t;
        acc[k] = 0.f;
    }
}
__global__ void fb_pool_kernel(const float* __restrict__ dinv, const float* __restrict__ g,
                               const float* __restrict__ acc, const float* __restrict__ coeff,
                               const int* __restrict__ batch, float* __restrict__ sums,
                               float* __restrict__ cnt, int n) {
    int i = blockIdx.x * blockDim.x + threadIdx.x;
    int stride = gridDim.x * blockDim.x;
    for (int k = i; k < n; k += stride) {
        float d = dinv[k];
        float t3 = d * (acc[k] + g[k]) + coeff[6];
        int b = batch[k];
        atomicAdd(&sums[b], t3);
        atomicAdd(&cnt[b], 1.0f);
    }
}
// ===========================================================================

extern "C" void kernel_launch(void* const* d_in, const int* in_sizes, int n_in,
                              void* d_out, int out_size, void* d_ws, size_t ws_size,
                              hipStream_t stream) {
    const float* x     = (const float*)d_in[0];
    const int*   ei    = (const int*)d_in[1];
    const int*   batch = (const int*)d_in[2];
    const float* W1    = (const float*)d_in[3];
    const float* b1    = (const float*)d_in[4];
    const float* W2    = (const float*)d_in[5];
    const float* b2    = (const float*)d_in[6];
    const float* W3    = (const float*)d_in[7];
    const float* b3    = (const float*)d_in[8];
    const float* lin_w = (const float*)d_in[9];
    const float* lin_b = (const float*)d_in[10];

    const int n       = in_sizes[0] / 4;   // 100000
    const int E       = in_sizes[1] / 2;   // 3200000
    const int ngraphs = out_size;          // 1000

    const int nbuck = (n + BSZ - 1) / BSZ;
    const int B = 256;

    size_t npad = ((size_t)n + 255) & ~(size_t)255;
    size_t gpad = ((size_t)ngraphs + 255) & ~(size_t)255;
    size_t mlen = (size_t)nbuck * NB_SCAT;
    int total   = (int)mlen;
    int nchunks = (total + SCAN_CHUNK - 1) / SCAN_CHUNK;

    size_t need = (256 + mlen + 1024 + (size_t)E + 3 * npad + 2 * gpad) * 4;

    float* ws   = (float*)d_ws;
    float* coeff = ws;                                    // 256
    unsigned* M    = (unsigned*)(coeff + 256);            // mlen
    unsigned* part = M + mlen;                            // <=1024
    unsigned* buck = part + 1024;                         // E (16B aligned)
    float* dinv  = (float*)(buck + E);                    // npad
    float* gA    = dinv + npad;                           // npad
    float* gB    = gA + npad;                             // npad
    float* sums  = gB + npad;                             // gpad
    float* cnt   = sums + gpad;                           // gpad

    coeffs_kernel<<<1, 64, 0, stream>>>(W1, b1, W2, b2, W3, b3, lin_w, lin_b, coeff);

    if (ws_size < need) {
        // -------- fallback: R1 atomic path (needs ~1.2 MB) --------
        float* deg = (float*)(ws + 256);
        float* g   = deg + npad;
        float* acc = g + npad;
        float* fsums = acc + npad;
        float* fcnt  = fsums + gpad;
        int nodeBlocks = (n + B - 1) / B;
        int edgeBlocks = (E + B - 1) / B;
        fb_init_kernel<<<nodeBlocks, B, 0, stream>>>(deg, fsums, fcnt, n, ngraphs);
        fb_deg_kernel<<<edgeBlocks, B, 0, stream>>>(ei + E, deg, E);
        fb_node0_kernel<<<nodeBlocks, B, 0, stream>>>(x, coeff, deg, g, acc, n);
        fb_edge_kernel<<<edgeBlocks, B, 0, stream>>>(ei, g, acc, E);
        fb_node_kernel<<<nodeBlocks, B, 0, stream>>>(deg, g, acc, coeff, 4, n);
        fb_edge_kernel<<<edgeBlocks, B, 0, stream>>>(ei, g, acc, E);
        fb_node_kernel<<<nodeBlocks, B, 0, stream>>>(deg, g, acc, coeff, 5, n);
        fb_edge_kernel<<<edgeBlocks, B, 0, stream>>>(ei, g, acc, E);
        fb_pool_kernel<<<nodeBlocks, B, 0, stream>>>(deg, g, acc, coeff, batch, fsums, fcnt, n);
        final_kernel<<<(ngraphs + B - 1) / B, B, 0, stream>>>(fsums, fcnt, coeff, (float*)d_out, ngraphs);
        return;
    }

    // tile rounded to multiple of 4 so every block's base is 16B-aligned
    int tile = (((E + NB_SCAT - 1) / NB_SCAT) + 3) & ~3;
    size_t ldsHist = (size_t)nbuck * sizeof(unsigned);

    zero_pool_kernel<<<(ngraphs + B - 1) / B, B, 0, stream>>>(sums, cnt, ngraphs);

    hist_kernel<<<NB_SCAT, B, ldsHist, stream>>>(ei + E, E, tile, nbuck, M);
    scan1_kernel<<<nchunks, B, 0, stream>>>(M, part, total, SCAN_CHUNK);
    scan2_kernel<<<1, 64, 0, stream>>>(part, nchunks);
    scan3_kernel<<<nchunks, B, 0, stream>>>(M, part, total, SCAN_CHUNK);
    scatter_kernel<<<NB_SCAT, B, ldsHist, stream>>>(ei, ei + E, E, tile, nbuck, M, buck);

    deg0_kernel<<<nbuck, B, 0, stream>>>(buck, M, nbuck, E, x, coeff, dinv, gA, n);

    gather_kernel<<<nbuck, B, 0, stream>>>(buck, M, nbuck, E, dinv, gA, gB, coeff, 4, n, 0);
    gather_kernel<<<nbuck, B, 0, stream>>>(buck, M, nbuck, E, dinv, gB, gA, coeff, 5, n, 0);
    gather_kernel<<<nbuck, B, 0, stream>>>(buck, M, nbuck, E, dinv, gA, gB, coeff, 6, n, 1);

    pool_kernel<<<(n + PNODES - 1) / PNODES, B, 0, stream>>>(gB, batch, sums, cnt, n);

    final_kernel<<<(ngraphs + B - 1) / B, B, 0, stream>>>(sums, cnt, coeff, (float*)d_out, ngraphs);
}

// Round 4
// 157.750 us; speedup vs baseline: 4.6917x; 1.1402x over previous
//
#include <hip/hip_runtime.h>
#include <math.h>

// ---------------------------------------------------------------------------
// GCN: 3x GCNConv (linear) -> mean pool -> linear -> sigmoid.
// Linear-collapse identity (absmax 0.0 through R3):
//   h3 @ lin_w = A(A(A(X u) + s2) + s1) + s0,  u = W1W2W3 lin_w.
// R3 profile: scatter = 55us with WRITE_SIZE 79MB for a 12.8MB array (6x
// write amp): 32B runs per (bucket,block) < 64B line -> false sharing across
// CUs + partial-line evictions. R4: bucket 64->256 nodes (SHIFT=8) so runs
// are ~128B (2 full lines); epilogues use all 256 threads.
// ---------------------------------------------------------------------------

#define SHIFT      8
#define BSZ        256         // nodes per bucket = 1<<SHIFT (== blockDim)
#define NB_SCAT    256         // blocks for hist/scatter phases
#define SCAN_CHUNK 2048
#define PNODES     1024        // nodes per pool block
#define ROWMASK    0x1FFFFu    // 17 bits for row id (n < 131072)

__global__ void coeffs_kernel(const float* __restrict__ W1, const float* __restrict__ b1,
                              const float* __restrict__ W2, const float* __restrict__ b2,
                              const float* __restrict__ W3, const float* __restrict__ b3,
                              const float* __restrict__ lin_w, const float* __restrict__ lin_b,
                              float* __restrict__ coeff) {
    if (threadIdx.x == 0 && blockIdx.x == 0) {
        float w3l[16], w2l[16];
        for (int i = 0; i < 16; ++i) {
            float s = 0.f;
            for (int j = 0; j < 16; ++j) s += W3[i * 16 + j] * lin_w[j];
            w3l[i] = s;
        }
        for (int i = 0; i < 16; ++i) {
            float s = 0.f;
            for (int j = 0; j < 16; ++j) s += W2[i * 16 + j] * w3l[j];
            w2l[i] = s;
        }
        for (int i = 0; i < 4; ++i) {
            float s = 0.f;
            for (int j = 0; j < 16; ++j) s += W1[i * 16 + j] * w2l[j];
            coeff[i] = s;
        }
        float s2 = 0.f, s1 = 0.f, s0 = 0.f;
        for (int j = 0; j < 16; ++j) {
            s2 += b1[j] * w2l[j];
            s1 += b2[j] * w3l[j];
            s0 += b3[j] * lin_w[j];
        }
        coeff[4] = s2; coeff[5] = s1; coeff[6] = s0; coeff[7] = lin_b[0];
    }
}

__global__ void zero_pool_kernel(float* __restrict__ sums, float* __restrict__ cnt, int ngraphs) {
    int i = blockIdx.x * blockDim.x + threadIdx.x;
    if (i < ngraphs) { sums[i] = 0.f; cnt[i] = 0.f; }
}

// ---- Phase A: per-block histogram of col>>SHIFT. M layout: [bin][block].
__global__ void hist_kernel(const int* __restrict__ col, int E, int tile, int nbuck,
                            unsigned* __restrict__ M) {
    extern __shared__ unsigned h[];
    for (int i = threadIdx.x; i < nbuck; i += blockDim.x) h[i] = 0;
    __syncthreads();
    int b = blockIdx.x;
    int s = b * tile, e = min(s + tile, E);          // s is multiple of 4 (tile rounded)
    if (s < e) {
        int nq = (e - s) >> 2;
        const int4* c4 = (const int4*)(col + s);
        for (int q = threadIdx.x; q < nq; q += blockDim.x) {
            int4 c = c4[q];
            atomicAdd(&h[((unsigned)c.x) >> SHIFT], 1u);
            atomicAdd(&h[((unsigned)c.y) >> SHIFT], 1u);
            atomicAdd(&h[((unsigned)c.z) >> SHIFT], 1u);
            atomicAdd(&h[((unsigned)c.w) >> SHIFT], 1u);
        }
        for (int k = s + (nq << 2) + threadIdx.x; k < e; k += blockDim.x)
            atomicAdd(&h[((unsigned)col[k]) >> SHIFT], 1u);
    }
    __syncthreads();
    for (int i = threadIdx.x; i < nbuck; i += blockDim.x)
        M[(size_t)i * NB_SCAT + b] = h[i];
}

// ---- exclusive scan over M (nbuck*NB_SCAT elems), 3-kernel hierarchy
__global__ void scan1_kernel(const unsigned* __restrict__ M, unsigned* __restrict__ part,
                             int total, int chunk) {
    __shared__ unsigned sdata[256];
    int b = blockIdx.x;
    int s = b * chunk, e = min(s + chunk, total);
    unsigned sum = 0;
    for (int k = s + threadIdx.x; k < e; k += blockDim.x) sum += M[k];
    sdata[threadIdx.x] = sum;
    __syncthreads();
    for (int off = 128; off > 0; off >>= 1) {
        if (threadIdx.x < off) sdata[threadIdx.x] += sdata[threadIdx.x + off];
        __syncthreads();
    }
    if (threadIdx.x == 0) part[b] = sdata[0];
}

__global__ void scan2_kernel(unsigned* __restrict__ part, int np) {
    if (threadIdx.x == 0 && blockIdx.x == 0) {
        unsigned run = 0;
        for (int i = 0; i < np; ++i) { unsigned v = part[i]; part[i] = run; run += v; }
    }
}

__global__ void scan3_kernel(unsigned* __restrict__ M, const unsigned* __restrict__ part,
                             int total, int chunk) {
    __shared__ unsigned ts[256];
    int b = blockIdx.x;
    int s = b * chunk;
    const int per = SCAN_CHUNK / 256;      // 8
    unsigned v[per];
    unsigned sum = 0;
    int base = s + threadIdx.x * per;
    for (int j = 0; j < per; ++j) {
        unsigned x = (base + j < total) ? M[base + j] : 0u;
        v[j] = sum; sum += x;
    }
    ts[threadIdx.x] = sum;
    __syncthreads();
    for (int off = 1; off < 256; off <<= 1) {
        unsigned t = (threadIdx.x >= (unsigned)off) ? ts[threadIdx.x - off] : 0u;
        __syncthreads();
        ts[threadIdx.x] += t;
        __syncthreads();
    }
    unsigned texcl = (threadIdx.x == 0) ? 0u : ts[threadIdx.x - 1];
    unsigned pb = part[b];
    for (int j = 0; j < per; ++j)
        if (base + j < total) M[base + j] = pb + texcl + v[j];
}

// ---- Phase B: scatter into buckets; pack row(17b) | col_low(8b)<<17
__global__ void scatter_kernel(const int* __restrict__ row, const int* __restrict__ col,
                               int E, int tile, int nbuck, const unsigned* __restrict__ M,
                               unsigned* __restrict__ out) {
    extern __shared__ unsigned base[];
    int b = blockIdx.x;
    for (int i = threadIdx.x; i < nbuck; i += blockDim.x)
        base[i] = M[(size_t)i * NB_SCAT + b];
    __syncthreads();
    int s = b * tile, e = min(s + tile, E);
    if (s < e) {
        int nq = (e - s) >> 2;
        const int4* r4 = (const int4*)(row + s);
        const int4* c4 = (const int4*)(col + s);
        for (int q = threadIdx.x; q < nq; q += blockDim.x) {
            int4 r = r4[q];
            int4 c = c4[q];
            unsigned p0 = atomicAdd(&base[((unsigned)c.x) >> SHIFT], 1u);
            unsigned p1 = atomicAdd(&base[((unsigned)c.y) >> SHIFT], 1u);
            unsigned p2 = atomicAdd(&base[((unsigned)c.z) >> SHIFT], 1u);
            unsigned p3 = atomicAdd(&base[((unsigned)c.w) >> SHIFT], 1u);
            out[p0] = (unsigned)r.x | (((unsigned)c.x & (BSZ - 1)) << 17);
            out[p1] = (unsigned)r.y | (((unsigned)c.y & (BSZ - 1)) << 17);
            out[p2] = (unsigned)r.z | (((unsigned)c.z & (BSZ - 1)) << 17);
            out[p3] = (unsigned)r.w | (((unsigned)c.w & (BSZ - 1)) << 17);
        }
        for (int k = s + (nq << 2) + threadIdx.x; k < e; k += blockDim.x) {
            unsigned c = (unsigned)col[k];
            unsigned pos = atomicAdd(&base[c >> SHIFT], 1u);
            out[pos] = (unsigned)row[k] | ((c & (BSZ - 1)) << 17);
        }
    }
}

// ---- deg (incoming count +1 self) -> dinv; fused with t0 = x.u, g0 = dinv*t0
__global__ void deg0_kernel(const unsigned* __restrict__ buck, const unsigned* __restrict__ M,
                            int nbuck, int E, const float* __restrict__ x,
                            const float* __restrict__ coeff, float* __restrict__ dinv,
                            float* __restrict__ g, int n) {
    __shared__ float acc[BSZ];
    int b = blockIdx.x;
    acc[threadIdx.x] = 0.f;
    __syncthreads();
    unsigned s = M[(size_t)b * NB_SCAT];
    unsigned e = (b + 1 < nbuck) ? M[(size_t)(b + 1) * NB_SCAT] : (unsigned)E;
    unsigned sa = (s + 3u) & ~3u;
    if (sa > e) sa = e;
    if (s + threadIdx.x < sa)
        atomicAdd(&acc[buck[s + threadIdx.x] >> 17], 1.0f);
    unsigned nq = (e - sa) >> 2;
    const uint4* bq = (const uint4*)(buck + sa);
    for (unsigned q = threadIdx.x; q < nq; q += blockDim.x) {
        uint4 w = bq[q];
        atomicAdd(&acc[w.x >> 17], 1.0f);
        atomicAdd(&acc[w.y >> 17], 1.0f);
        atomicAdd(&acc[w.z >> 17], 1.0f);
        atomicAdd(&acc[w.w >> 17], 1.0f);
    }
    for (unsigned k = sa + (nq << 2) + threadIdx.x; k < e; k += blockDim.x)
        atomicAdd(&acc[buck[k] >> 17], 1.0f);
    __syncthreads();
    int node = b * BSZ + threadIdx.x;
    if (node < n) {
        float d = rsqrtf(acc[threadIdx.x] + 1.0f);
        dinv[node] = d;
        float4 xv = ((const float4*)x)[node];
        float t0 = xv.x * coeff[0] + xv.y * coeff[1] + xv.z * coeff[2] + xv.w * coeff[3];
        g[node] = d * t0;
    }
}

// ---- one propagation pass: acc_c = sum g[row]; t = dinv*(acc+g)+s
// passes 1,2: gout = dinv*t.  pass 3 (lastPass): gout = t (t3, pooled later).
__global__ void gather_kernel(const unsigned* __restrict__ buck, const unsigned* __restrict__ M,
                              int nbuck, int E, const float* __restrict__ dinv,
                              const float* __restrict__ gin, float* __restrict__ gout,
                              const float* __restrict__ coeff, int sidx, int n, int lastPass) {
    __shared__ float acc[BSZ];
    int b = blockIdx.x;
    acc[threadIdx.x] = 0.f;
    __syncthreads();
    unsigned s = M[(size_t)b * NB_SCAT];
    unsigned e = (b + 1 < nbuck) ? M[(size_t)(b + 1) * NB_SCAT] : (unsigned)E;
    unsigned sa = (s + 3u) & ~3u;
    if (sa > e) sa = e;
    if (s + threadIdx.x < sa) {
        unsigned w = buck[s + threadIdx.x];
        atomicAdd(&acc[w >> 17], gin[w & ROWMASK]);
    }
    unsigned nq = (e - sa) >> 2;
    const uint4* bq = (const uint4*)(buck + sa);
    for (unsigned q = threadIdx.x; q < nq; q += blockDim.x) {
        uint4 w = bq[q];
        float a0 = gin[w.x & ROWMASK];     // 4 independent gathers in flight
        float a1 = gin[w.y & ROWMASK];
        float a2 = gin[w.z & ROWMASK];
        float a3 = gin[w.w & ROWMASK];
        atomicAdd(&acc[w.x >> 17], a0);
        atomicAdd(&acc[w.y >> 17], a1);
        atomicAdd(&acc[w.z >> 17], a2);
        atomicAdd(&acc[w.w >> 17], a3);
    }
    for (unsigned k = sa + (nq << 2) + threadIdx.x; k < e; k += blockDim.x) {
        unsigned w = buck[k];
        atomicAdd(&acc[w >> 17], gin[w & ROWMASK]);
    }
    __syncthreads();
    int node = b * BSZ + threadIdx.x;
    if (node < n) {
        float d = dinv[node];
        float t = d * (acc[threadIdx.x] + gin[node]) + coeff[sidx];
        gout[node] = lastPass ? t : d * t;
    }
}

// ---- segmented mean-pool using SORTED batch: LDS slots + sparse atomics
__global__ void pool_kernel(const float* __restrict__ t3, const int* __restrict__ batch,
                            float* __restrict__ sums, float* __restrict__ cnt, int n) {
    __shared__ float ls[1024];
    __shared__ float lc[1024];
    int s = blockIdx.x * PNODES, e = min(s + PNODES, n);
    if (s >= e) return;
    int bFirst = batch[s];
    int bLast  = batch[e - 1];
    int range = bLast - bFirst + 1;
    if (range <= 1024) {
        for (int i = threadIdx.x; i < range; i += blockDim.x) { ls[i] = 0.f; lc[i] = 0.f; }
        __syncthreads();
        for (int k = s + threadIdx.x; k < e; k += blockDim.x) {
            int bb = batch[k] - bFirst;
            atomicAdd(&ls[bb], t3[k]);
            atomicAdd(&lc[bb], 1.0f);
        }
        __syncthreads();
        for (int i = threadIdx.x; i < range; i += blockDim.x) {
            if (lc[i] != 0.f) {
                atomicAdd(&sums[bFirst + i], ls[i]);
                atomicAdd(&cnt[bFirst + i], lc[i]);
            }
        }
    } else {  // defensive fallback (unreachable for ngraphs<=1024)
        for (int k = s + threadIdx.x; k < e; k += blockDim.x) {
            atomicAdd(&sums[batch[k]], t3[k]);
            atomicAdd(&cnt[batch[k]], 1.0f);
        }
    }
}

__global__ void final_kernel(const float* __restrict__ sums, const float* __restrict__ cnt,
                             const float* __restrict__ coeff, float* __restrict__ out,
                             int ngraphs) {
    int i = blockIdx.x * blockDim.x + threadIdx.x;
    if (i < ngraphs) {
        float m = sums[i] / fmaxf(cnt[i], 1.0f) + coeff[7];
        out[i] = 1.0f / (1.0f + expf(-m));
    }
}

// ======================= R1 fallback (atomic path) =========================
__global__ void fb_init_kernel(float* __restrict__ deg, float* __restrict__ sums,
                               float* __restrict__ cnt, int n, int ngraphs) {
    int i = blockIdx.x * blockDim.x + threadIdx.x;
    int stride = gridDim.x * blockDim.x;
    for (int k = i; k < n; k += stride) deg[k] = 1.0f;
    for (int k = i; k < ngraphs; k += stride) { sums[k] = 0.f; cnt[k] = 0.f; }
}
__global__ void fb_deg_kernel(const int* __restrict__ col, float* __restrict__ deg, int E) {
    int i = blockIdx.x * blockDim.x + threadIdx.x;
    int stride = gridDim.x * blockDim.x;
    for (int k = i; k < E; k += stride) atomicAdd(&deg[col[k]], 1.0f);
}
__global__ void fb_node0_kernel(const float* __restrict__ x, const float* __restrict__ coeff,
                                float* __restrict__ deg_dinv, float* __restrict__ g,
                                float* __restrict__ acc, int n) {
    int i = blockIdx.x * blockDim.x + threadIdx.x;
    int stride = gridDim.x * blockDim.x;
    for (int k = i; k < n; k += stride) {
        float d = rsqrtf(deg_dinv[k]);
        deg_dinv[k] = d;
        float4 xv = ((const float4*)x)[k];
        float t0 = xv.x * coeff[0] + xv.y * coeff[1] + xv.z * coeff[2] + xv.w * coeff[3];
        g[k] = d * t0;
        acc[k] = 0.f;
    }
}
__global__ void fb_edge_kernel(const int* __restrict__ ei, const float* __restrict__ g,
                               float* __restrict__ acc, int E) {
    int i = blockIdx.x * blockDim.x + threadIdx.x;
    int stride = gridDim.x * blockDim.x;
    for (int k = i; k < E; k += stride) atomicAdd(&acc[ei[E + k]], g[ei[k]]);
}
__global__ void fb_node_kernel(const float* __restrict__ dinv, float* __restrict__ g,
                               float* __restrict__ acc, const float* __restrict__ coeff,
                               int sidx, int n) {
    int i = blockIdx.x * blockDim.x + threadIdx.x;
    int stride = gridDim.x * blockDim.x;
    for (int k = i; k < n; k += stride) {
        float d = dinv[k];
        float t = d * (acc[k] + g[k]) + coeff[sidx];
        g[k] = d * t;
        acc[k] = 0.f;
    }
}
__global__ void fb_pool_kernel(const float* __restrict__ dinv, const float* __restrict__ g,
                               const float* __restrict__ acc, const float* __restrict__ coeff,
                               const int* __restrict__ batch, float* __restrict__ sums,
                               float* __restrict__ cnt, int n) {
    int i = blockIdx.x * blockDim.x + threadIdx.x;
    int stride = gridDim.x * blockDim.x;
    for (int k = i; k < n; k += stride) {
        float d = dinv[k];
        float t3 = d * (acc[k] + g[k]) + coeff[6];
        int b = batch[k];
        atomicAdd(&sums[b], t3);
        atomicAdd(&cnt[b], 1.0f);
    }
}
// ===========================================================================

extern "C" void kernel_launch(void* const* d_in, const int* in_sizes, int n_in,
                              void* d_out, int out_size, void* d_ws, size_t ws_size,
                              hipStream_t stream) {
    const float* x     = (const float*)d_in[0];
    const int*   ei    = (const int*)d_in[1];
    const int*   batch = (const int*)d_in[2];
    const float* W1    = (const float*)d_in[3];
    const float* b1    = (const float*)d_in[4];
    const float* W2    = (const float*)d_in[5];
    const float* b2    = (const float*)d_in[6];
    const float* W3    = (const float*)d_in[7];
    const float* b3    = (const float*)d_in[8];
    const float* lin_w = (const float*)d_in[9];
    const float* lin_b = (const float*)d_in[10];

    const int n       = in_sizes[0] / 4;   // 100000
    const int E       = in_sizes[1] / 2;   // 3200000
    const int ngraphs = out_size;          // 1000

    const int nbuck = (n + BSZ - 1) / BSZ; // 391
    const int B = 256;

    size_t npad = ((size_t)n + 255) & ~(size_t)255;
    size_t gpad = ((size_t)ngraphs + 255) & ~(size_t)255;
    size_t mlen = (size_t)nbuck * NB_SCAT;
    int total   = (int)mlen;
    int nchunks = (total + SCAN_CHUNK - 1) / SCAN_CHUNK;

    size_t need = (256 + mlen + 1024 + (size_t)E + 3 * npad + 2 * gpad) * 4;

    float* ws   = (float*)d_ws;
    float* coeff = ws;                                    // 256
    unsigned* M    = (unsigned*)(coeff + 256);            // mlen
    unsigned* part = M + mlen;                            // <=1024
    unsigned* buck = part + 1024;                         // E (16B aligned)
    float* dinv  = (float*)(buck + E);                    // npad
    float* gA    = dinv + npad;                           // npad
    float* gB    = gA + npad;                             // npad
    float* sums  = gB + npad;                             // gpad
    float* cnt   = sums + gpad;                           // gpad

    coeffs_kernel<<<1, 64, 0, stream>>>(W1, b1, W2, b2, W3, b3, lin_w, lin_b, coeff);

    if (ws_size < need) {
        // -------- fallback: R1 atomic path (needs ~1.2 MB) --------
        float* deg = (float*)(ws + 256);
        float* g   = deg + npad;
        float* acc = g + npad;
        float* fsums = acc + npad;
        float* fcnt  = fsums + gpad;
        int nodeBlocks = (n + B - 1) / B;
        int edgeBlocks = (E + B - 1) / B;
        fb_init_kernel<<<nodeBlocks, B, 0, stream>>>(deg, fsums, fcnt, n, ngraphs);
        fb_deg_kernel<<<edgeBlocks, B, 0, stream>>>(ei + E, deg, E);
        fb_node0_kernel<<<nodeBlocks, B, 0, stream>>>(x, coeff, deg, g, acc, n);
        fb_edge_kernel<<<edgeBlocks, B, 0, stream>>>(ei, g, acc, E);
        fb_node_kernel<<<nodeBlocks, B, 0, stream>>>(deg, g, acc, coeff, 4, n);
        fb_edge_kernel<<<edgeBlocks, B, 0, stream>>>(ei, g, acc, E);
        fb_node_kernel<<<nodeBlocks, B, 0, stream>>>(deg, g, acc, coeff, 5, n);
        fb_edge_kernel<<<edgeBlocks, B, 0, stream>>>(ei, g, acc, E);
        fb_pool_kernel<<<nodeBlocks, B, 0, stream>>>(deg, g, acc, coeff, batch, fsums, fcnt, n);
        final_kernel<<<(ngraphs + B - 1) / B, B, 0, stream>>>(fsums, fcnt, coeff, (float*)d_out, ngraphs);
        return;
    }

    // tile rounded to multiple of 4 so every block's base is 16B-aligned
    int tile = (((E + NB_SCAT - 1) / NB_SCAT) + 3) & ~3;
    size_t ldsHist = (size_t)nbuck * sizeof(unsigned);

    zero_pool_kernel<<<(ngraphs + B - 1) / B, B, 0, stream>>>(sums, cnt, ngraphs);

    hist_kernel<<<NB_SCAT, B, ldsHist, stream>>>(ei + E, E, tile, nbuck, M);
    scan1_kernel<<<nchunks, B, 0, stream>>>(M, part, total, SCAN_CHUNK);
    scan2_kernel<<<1, 64, 0, stream>>>(part, nchunks);
    scan3_kernel<<<nchunks, B, 0, stream>>>(M, part, total, SCAN_CHUNK);
    scatter_kernel<<<NB_SCAT, B, ldsHist, stream>>>(ei, ei + E, E, tile, nbuck, M, buck);

    deg0_kernel<<<nbuck, B, 0, stream>>>(buck, M, nbuck, E, x, coeff, dinv, gA, n);

    gather_kernel<<<nbuck, B, 0, stream>>>(buck, M, nbuck, E, dinv, gA, gB, coeff, 4, n, 0);
    gather_kernel<<<nbuck, B, 0, stream>>>(buck, M, nbuck, E, dinv, gB, gA, coeff, 5, n, 0);
    gather_kernel<<<nbuck, B, 0, stream>>>(buck, M, nbuck, E, dinv, gA, gB, coeff, 6, n, 1);

    pool_kernel<<<(n + PNODES - 1) / PNODES, B, 0, stream>>>(gB, batch, sums, cnt, n);

    final_kernel<<<(ngraphs + B - 1) / B, B, 0, stream>>>(sums, cnt, coeff, (float*)d_out, ngraphs);
}